// Round 1
// 442.928 us; speedup vs baseline: 1.0029x; 1.0029x over previous
//
#include <hip/hip_runtime.h>

#define L_TOT   4096
#define CIN     32
#define G_L     4            // locations per block (same output row)
#define CH      4            // stages per chunk (stage s = c*3+ki, feature i = 3s+kj)
#define NCHUNK  24           // 96 stages total
#define CHUNK_STRIDE_F (CH * 3 * 64)   // 768 floats = 3072 B per location per chunk
// LDS: xs 36864 B + wsm 3*12288 B = 73728 B -> still 2 blocks/CU (<= 80 KB)

using f32g = __attribute__((address_space(1))) const float;
using f32l = __attribute__((address_space(3))) float;

// 16 FMAs: acc[bq][j] += PP.bq * WW.j  (param names must avoid x/y/z/w)
#define FMA16(PP, WW) {                                                        \
    acc[0][0] += PP.x * WW.x; acc[0][1] += PP.x * WW.y;                        \
    acc[0][2] += PP.x * WW.z; acc[0][3] += PP.x * WW.w;                        \
    acc[1][0] += PP.y * WW.x; acc[1][1] += PP.y * WW.y;                        \
    acc[1][2] += PP.y * WW.z; acc[1][3] += PP.y * WW.w;                        \
    acc[2][0] += PP.z * WW.x; acc[2][1] += PP.z * WW.y;                        \
    acc[2][2] += PP.z * WW.z; acc[2][3] += PP.z * WW.w;                        \
    acc[3][0] += PP.w * WW.x; acc[3][1] += PP.w * WW.y;                        \
    acc[3][2] += PP.w * WW.z; acc[3][3] += PP.w * WW.w; }

// compute one 4-stage chunk K out of LDS buffer at float-offset WOFF in wsm
#define COMPUTE4(K, WOFF) {                                                    \
    _Pragma("unroll")                                                          \
    for (int sl = 0; sl < CH; ++sl) {                                          \
        const int s = ((K) << 2) + sl;                                         \
        const float* pr = xs + ((6 * s + g) << 4) + (wv << 2);                 \
        float4 p0 = *(const float4*)(pr);                                      \
        float4 p1 = *(const float4*)(pr + 16);                                 \
        float4 p2 = *(const float4*)(pr + 32);                                 \
        const float4* wr = (const float4*)(&wsm[0][0] + (WOFF))                \
                           + g * 192 + sl * 48 + o4;                           \
        float4 w0 = wr[0];                                                     \
        float4 w1 = wr[16];                                                    \
        float4 w2 = wr[32];                                                    \
        FMA16(p0, w0); FMA16(p1, w1); FMA16(p2, w2);                           \
    } }

__global__ __launch_bounds__(256, 2)
void lc2d_v7(const float* __restrict__ x,
             const float* __restrict__ weight,
             const float* __restrict__ bias,
             float* __restrict__ out) {
    __shared__ __align__(16) float xs[576 * 16];     // [row=(c*3+dh)*6+wl][b]
    __shared__ __align__(16) float wsm[3][12 * 256]; // [buf][3072 floats = 12 KB]

    const int tid  = threadIdx.x;
    const int lane = tid & 63;
    const int wv   = tid >> 6;        // wave id -> b-quad base 4*wv
    const int g    = lane >> 4;       // location offset 0..3
    const int o4   = lane & 15;       // o-quad (o = 4*o4 .. 4*o4+3)

    // XCD-contiguous bijective remap: 1024 blocks = 8 XCDs * 128.
    // XCD x owns locations [x*512, x*512+512): 64B out lines (4 blocks) merge in
    // ONE L2 before eviction; x-tile rows reuse within the XCD's L2.
    const int bid  = blockIdx.x;
    const int swz  = ((bid & 7) << 7) | (bid >> 3);
    const int l0   = swz * G_L;
    const int oh   = l0 >> 6;
    const int ow0  = l0 & 63;

    // ---- per-wave DMA piece setup: pieces p = wv, wv+4, wv+8 of each 12 KB chunk
    // piece p covers bytes [p*1024, p*1024+1024) of the chunk;
    // chunk layout = 4 l-slabs of 3072 B (l = l0+gg, gg = p/3), i-major within slab.
    const float* gsrc[3];
    int ldsoff[3];
#pragma unroll
    for (int t = 0; t < 3; ++t) {
        int p   = wv + (t << 2);      // 0..11, wave-uniform
        int gg  = p / 3;
        int sub = p - 3 * gg;
        gsrc[t] = weight + (size_t)(l0 + gg) * (288 * 64) + sub * 256 + (lane << 2);
        ldsoff[t] = p * 256;          // float offset of piece base in wsm[buf]
    }

    // ---- prologue: DMA chunks 0 AND 1 (2-deep) while filling the x tile ----
#pragma unroll
    for (int t = 0; t < 3; ++t)
        __builtin_amdgcn_global_load_lds((f32g*)(gsrc[t]),
                                         (f32l*)(&wsm[0][ldsoff[t]]), 16, 0, 0);
#pragma unroll
    for (int t = 0; t < 3; ++t)
        __builtin_amdgcn_global_load_lds((f32g*)(gsrc[t] + CHUNK_STRIDE_F),
                                         (f32l*)(&wsm[1][ldsoff[t]]), 16, 0, 0);

    for (int u = tid; u < 1536; u += 256) {       // u = (c*3+dh)*16 + b
        int b  = u & 15;
        int t  = u >> 4;              // c*3 + dh
        int dh = t % 3;
        int c  = t / 3;
        int h  = oh - 1 + dh;
        bool hok = (unsigned)h < 64u;
        const float* xrow = x + (((b * CIN + c) * 64 + h) << 6);
        int wbase = ow0 - 1;
#pragma unroll
        for (int wl = 0; wl < 6; ++wl) {
            int ww = wbase + wl;
            float v = (hok && (unsigned)ww < 64u) ? xrow[ww] : 0.0f;
            xs[(t * 6 + wl) * 16 + b] = v;
        }
    }
    __syncthreads();   // full drain: DMA(0),DMA(1) + x fill resident for everyone

    const float4 bias4 = ((const float4*)bias)[(l0 + g) * 16 + o4];
    float acc[4][4];
#pragma unroll
    for (int bq = 0; bq < 4; ++bq) {
        acc[bq][0] = bias4.x; acc[bq][1] = bias4.y;
        acc[bq][2] = bias4.z; acc[bq][3] = bias4.w;
    }

    // ---- main pipeline (T3+T4): 3 buffers, 2 chunks in flight, NEVER vmcnt(0).
    // iter k: issue DMA(k+2) into the buffer freed at iter k-1, compute(k),
    // then wait vmcnt(3): exactly the 3 newest loads (DMA(k+2)) may remain in
    // flight -> DMA(k+1) is guaranteed landed (in-order retirement), and it had
    // ~2 full compute phases of flight time. lgkmcnt(0) drains our ds_reads of
    // buffer k before anyone can overwrite it after the barrier.
    int wo0 = 0;              // holds chunk k
    int wo1 = 12 * 256;       // holds chunk k+1
    int wo2 = 2 * 12 * 256;   // DMA target for chunk k+2
    for (int k = 0; k < NCHUNK - 2; ++k) {
#pragma unroll
        for (int t = 0; t < 3; ++t)
            __builtin_amdgcn_global_load_lds(
                (f32g*)(gsrc[t] + (size_t)(k + 2) * CHUNK_STRIDE_F),
                (f32l*)(&wsm[0][0] + wo2 + ldsoff[t]), 16, 0, 0);
        COMPUTE4(k, wo0);
        asm volatile("s_waitcnt vmcnt(3) lgkmcnt(0)" ::: "memory");
        __builtin_amdgcn_s_barrier();
        asm volatile("" ::: "memory");
        int tmp = wo0; wo0 = wo1; wo1 = wo2; wo2 = tmp;
    }
    // tail: chunk 22 already resident; drain DMA(23) fully, then finish
    COMPUTE4(NCHUNK - 2, wo0);
    asm volatile("s_waitcnt vmcnt(0) lgkmcnt(0)" ::: "memory");
    __builtin_amdgcn_s_barrier();
    asm volatile("" ::: "memory");
    COMPUTE4(NCHUNK - 1, wo1);

    // ---- stores: out[((b*64 + o) << 12) + l0 + g], b = 4*wv+bq, o = 4*o4+j
#pragma unroll
    for (int bq = 0; bq < 4; ++bq) {
        const int b = (wv << 2) + bq;
#pragma unroll
        for (int j = 0; j < 4; ++j) {
            out[((size_t)((b << 6) + (o4 << 2) + j) << 12) + l0 + g] = acc[bq][j];
        }
    }
}

extern "C" void kernel_launch(void* const* d_in, const int* in_sizes, int n_in,
                              void* d_out, int out_size, void* d_ws, size_t ws_size,
                              hipStream_t stream) {
    const float* x      = (const float*)d_in[0];
    const float* weight = (const float*)d_in[1];
    const float* bias   = (const float*)d_in[2];
    float* out          = (float*)d_out;

    dim3 grid(L_TOT / G_L);   // 1024 blocks = 2 resident/CU, 4 total/CU
    dim3 block(256);
    hipLaunchKernelGGL(lc2d_v7, grid, block, 0, stream, x, weight, bias, out);
}

// Round 3
// 427.275 us; speedup vs baseline: 1.0396x; 1.0366x over previous
//
#include <hip/hip_runtime.h>

#define L_TOT   4096
#define CIN     32
#define G_L     4            // locations per block (same output row)
#define CH      4            // stages per chunk (stage s = c*3+ki, feature i = 3s+kj)
#define NCHUNK  24           // 96 stages total
#define CHUNK_STRIDE_F (CH * 3 * 64)   // 768 floats = 3072 B per location per chunk
#define XT_FLOATS (32 * 64 * 64 * 16)  // xT[c][h][w][b] = 2M floats = 8 MB
// LDS: xs 36864 B + wsm 3*12288 B = 73728 B -> 2 blocks/CU (147456 <= 163840)

using f32g = __attribute__((address_space(1))) const float;
using f32l = __attribute__((address_space(3))) float;

// ---- pre-kernel: transpose x (B,C,H,W) -> xT[c][h][w][b] so the main kernel's
// x-fill is b-contiguous (float4 per 4 batches, 64 B-line dense).
__global__ __launch_bounds__(256, 4)
void xt_kernel(const float* __restrict__ x, float* __restrict__ xT) {
    const int bi  = blockIdx.x;            // c*64 + h
    const int c   = bi >> 6;
    const int h   = bi & 63;
    const int tid = threadIdx.x;
    const int w   = tid >> 2;              // 0..63
    const int bq  = tid & 3;               // 0..3 -> b = 4*bq+j
    const int base = (((c << 6) + h) << 6) + w;   // (c*64+h)*64 + w
    float4 v;
    v.x = x[((bq << 2) + 0) * 131072 + base];     // 131072 = CIN*64*64
    v.y = x[((bq << 2) + 1) * 131072 + base];
    v.z = x[((bq << 2) + 2) * 131072 + base];
    v.w = x[((bq << 2) + 3) * 131072 + base];
    *(float4*)(xT + base * 16 + (bq << 2)) = v;
}

// 16 FMAs: acc[bq][j] += PP.bq * WW.j  (param names must avoid x/y/z/w)
#define FMA16(PP, WW) {                                                        \
    acc[0][0] += PP.x * WW.x; acc[0][1] += PP.x * WW.y;                        \
    acc[0][2] += PP.x * WW.z; acc[0][3] += PP.x * WW.w;                        \
    acc[1][0] += PP.y * WW.x; acc[1][1] += PP.y * WW.y;                        \
    acc[1][2] += PP.y * WW.z; acc[1][3] += PP.y * WW.w;                        \
    acc[2][0] += PP.z * WW.x; acc[2][1] += PP.z * WW.y;                        \
    acc[2][2] += PP.z * WW.z; acc[2][3] += PP.z * WW.w;                        \
    acc[3][0] += PP.w * WW.x; acc[3][1] += PP.w * WW.y;                        \
    acc[3][2] += PP.w * WW.z; acc[3][3] += PP.w * WW.w; }

// compute one 4-stage chunk K out of LDS buffer at float-offset WOFF in wsm
#define COMPUTE4(K, WOFF) {                                                    \
    _Pragma("unroll")                                                          \
    for (int sl = 0; sl < CH; ++sl) {                                          \
        const int s = ((K) << 2) + sl;                                         \
        const float* pr = xs + ((6 * s + g) << 4) + (wv << 2);                 \
        float4 p0 = *(const float4*)(pr);                                      \
        float4 p1 = *(const float4*)(pr + 16);                                 \
        float4 p2 = *(const float4*)(pr + 32);                                 \
        const float4* wr = (const float4*)(&wsm[0][0] + (WOFF))                \
                           + g * 192 + sl * 48 + o4;                           \
        float4 w0 = wr[0];                                                     \
        float4 w1 = wr[16];                                                    \
        float4 w2 = wr[32];                                                    \
        FMA16(p0, w0); FMA16(p1, w1); FMA16(p2, w2);                           \
    } }

template <int USE_XT>
__global__ __launch_bounds__(256, 2)
void lc2d_v8(const float* __restrict__ x,
             const float* __restrict__ xT,
             const float* __restrict__ weight,
             const float* __restrict__ bias,
             float* __restrict__ out) {
    __shared__ __align__(16) float xs[576 * 16];     // [row=(c*3+dh)*6+wl][b]
    __shared__ __align__(16) float wsm[3][12 * 256]; // [buf][3072 floats = 12 KB]

    const int tid  = threadIdx.x;
    const int lane = tid & 63;
    const int wv   = tid >> 6;        // wave id -> b-quad base 4*wv
    const int g    = lane >> 4;       // location offset 0..3
    const int o4   = lane & 15;       // o-quad (o = 4*o4 .. 4*o4+3)

    // XCD-contiguous bijective remap: 1024 blocks = 8 XCDs * 128.
    const int bid  = blockIdx.x;
    const int swz  = ((bid & 7) << 7) | (bid >> 3);
    const int l0   = swz * G_L;
    const int oh   = l0 >> 6;
    const int ow0  = l0 & 63;

    // ---- per-wave DMA piece setup: pieces p = wv, wv+4, wv+8 of each 12 KB chunk
    const float* gsrc[3];
    int ldsoff[3];
#pragma unroll
    for (int t = 0; t < 3; ++t) {
        int p   = wv + (t << 2);      // 0..11, wave-uniform
        int gg  = p / 3;
        int sub = p - 3 * gg;
        gsrc[t] = weight + (size_t)(l0 + gg) * (288 * 64) + sub * 256 + (lane << 2);
        ldsoff[t] = p * 256;          // float offset of piece base in wsm[buf]
    }

    // ---- prologue: DMA chunks 0 AND 1 (2-deep) while filling the x tile ----
#pragma unroll
    for (int t = 0; t < 3; ++t)
        __builtin_amdgcn_global_load_lds((f32g*)(gsrc[t]),
                                         (f32l*)(&wsm[0][ldsoff[t]]), 16, 0, 0);
#pragma unroll
    for (int t = 0; t < 3; ++t)
        __builtin_amdgcn_global_load_lds((f32g*)(gsrc[t] + CHUNK_STRIDE_F),
                                         (f32l*)(&wsm[1][ldsoff[t]]), 16, 0, 0);

    if (USE_XT) {
        // coalesced fill from xT[c][h][w][b]: 9 float4 loads/thread,
        // runs of 384 B dense per t-group (~600 line requests vs 9216).
#pragma unroll
        for (int i = 0; i < 9; ++i) {
            int e   = tid + (i << 8);     // 0..2303
            int b4  = e & 3;
            int row = e >> 2;             // t*6 + wl, 0..575
            int t   = row / 6;
            int wl  = row - 6 * t;
            int c   = t / 3;
            int dh  = t - 3 * c;
            int h   = oh - 1 + dh;
            int ww  = ow0 - 1 + wl;
            float4 v = {0.f, 0.f, 0.f, 0.f};
            if (((unsigned)h < 64u) && ((unsigned)ww < 64u))
                v = *(const float4*)(xT + ((((c << 6) + h) << 6) + ww) * 16 + (b4 << 2));
            *(float4*)(&xs[(row << 4) + (b4 << 2)]) = v;
        }
    } else {
        // fallback (ws too small): original scalar gather from x
        for (int u = tid; u < 1536; u += 256) {   // u = (c*3+dh)*16 + b
            int b  = u & 15;
            int t  = u >> 4;              // c*3 + dh
            int dh = t % 3;
            int c  = t / 3;
            int h  = oh - 1 + dh;
            bool hok = (unsigned)h < 64u;
            const float* xrow = x + (((b * CIN + c) * 64 + h) << 6);
            int wbase = ow0 - 1;
#pragma unroll
            for (int wl = 0; wl < 6; ++wl) {
                int ww = wbase + wl;
                float v = (hok && (unsigned)ww < 64u) ? xrow[ww] : 0.0f;
                xs[(t * 6 + wl) * 16 + b] = v;
            }
        }
    }
    __syncthreads();   // full drain: DMA(0),DMA(1) + x fill resident for everyone

    const float4 bias4 = ((const float4*)bias)[(l0 + g) * 16 + o4];
    float acc[4][4];
#pragma unroll
    for (int bq = 0; bq < 4; ++bq) {
        acc[bq][0] = bias4.x; acc[bq][1] = bias4.y;
        acc[bq][2] = bias4.z; acc[bq][3] = bias4.w;
    }

    // ---- main pipeline: 3 buffers, 2 chunks in flight, never vmcnt(0).
    int wo0 = 0;              // holds chunk k
    int wo1 = 12 * 256;       // holds chunk k+1
    int wo2 = 2 * 12 * 256;   // DMA target for chunk k+2
    for (int k = 0; k < NCHUNK - 2; ++k) {
#pragma unroll
        for (int t = 0; t < 3; ++t)
            __builtin_amdgcn_global_load_lds(
                (f32g*)(gsrc[t] + (size_t)(k + 2) * CHUNK_STRIDE_F),
                (f32l*)(&wsm[0][0] + wo2 + ldsoff[t]), 16, 0, 0);
        COMPUTE4(k, wo0);
        asm volatile("s_waitcnt vmcnt(3) lgkmcnt(0)" ::: "memory");
        __builtin_amdgcn_s_barrier();
        asm volatile("" ::: "memory");
        int tmp = wo0; wo0 = wo1; wo1 = wo2; wo2 = tmp;
    }
    // tail: chunk 22 resident; drain DMA(23) fully, then finish
    COMPUTE4(NCHUNK - 2, wo0);
    asm volatile("s_waitcnt vmcnt(0) lgkmcnt(0)" ::: "memory");
    __builtin_amdgcn_s_barrier();
    asm volatile("" ::: "memory");
    COMPUTE4(NCHUNK - 1, wo1);

    // ---- stores: out[((b*64 + o) << 12) + l0 + g], b = 4*wv+bq, o = 4*o4+j
#pragma unroll
    for (int bq = 0; bq < 4; ++bq) {
        const int b = (wv << 2) + bq;
#pragma unroll
        for (int j = 0; j < 4; ++j) {
            out[((size_t)((b << 6) + (o4 << 2) + j) << 12) + l0 + g] = acc[bq][j];
        }
    }
}

extern "C" void kernel_launch(void* const* d_in, const int* in_sizes, int n_in,
                              void* d_out, int out_size, void* d_ws, size_t ws_size,
                              hipStream_t stream) {
    const float* x      = (const float*)d_in[0];
    const float* weight = (const float*)d_in[1];
    const float* bias   = (const float*)d_in[2];
    float* out          = (float*)d_out;

    const size_t xt_bytes = (size_t)XT_FLOATS * 4;   // 8 MB
    dim3 grid(L_TOT / G_L);   // 1024 blocks
    dim3 block(256);
    if (d_ws != nullptr && ws_size >= xt_bytes) {
        float* xT = (float*)d_ws;
        hipLaunchKernelGGL(xt_kernel, dim3(32 * 64), dim3(256), 0, stream, x, xT);
        hipLaunchKernelGGL((lc2d_v8<1>), grid, block, 0, stream,
                           x, (const float*)xT, weight, bias, out);
    } else {
        hipLaunchKernelGGL((lc2d_v8<0>), grid, block, 0, stream,
                           x, (const float*)nullptr, weight, bias, out);
    }
}

// Round 4
// 427.064 us; speedup vs baseline: 1.0401x; 1.0005x over previous
//
#include <hip/hip_runtime.h>

#define L_TOT   4096
#define CIN     32
#define G_L     4            // locations per block (same output row)
#define CH      4            // stages per chunk (stage s = c*3+ki, feature i = 3s+kj)
#define NCHUNK  24           // 96 stages total
#define CHUNK_STRIDE_F (CH * 3 * 64)   // 768 floats = 3072 B per location per chunk
// LDS: xs 36864 B + wsm 3*12288 B = 73728 B -> 2 blocks/CU (147456 <= 163840)

using f32g = __attribute__((address_space(1))) const float;
using f32l = __attribute__((address_space(3))) float;

// 16 FMAs: acc[bq][j] += PP.bq * WW.j  (param names must avoid x/y/z/w)
#define FMA16(PP, WW) {                                                        \
    acc[0][0] += PP.x * WW.x; acc[0][1] += PP.x * WW.y;                        \
    acc[0][2] += PP.x * WW.z; acc[0][3] += PP.x * WW.w;                        \
    acc[1][0] += PP.y * WW.x; acc[1][1] += PP.y * WW.y;                        \
    acc[1][2] += PP.y * WW.z; acc[1][3] += PP.y * WW.w;                        \
    acc[2][0] += PP.z * WW.x; acc[2][1] += PP.z * WW.y;                        \
    acc[2][2] += PP.z * WW.z; acc[2][3] += PP.z * WW.w;                        \
    acc[3][0] += PP.w * WW.x; acc[3][1] += PP.w * WW.y;                        \
    acc[3][2] += PP.w * WW.z; acc[3][3] += PP.w * WW.w; }

// compute one 4-stage chunk K out of LDS buffer at float-offset WOFF in wsm
#define COMPUTE4(K, WOFF) {                                                    \
    _Pragma("unroll")                                                          \
    for (int sl = 0; sl < CH; ++sl) {                                          \
        const int s = ((K) << 2) + sl;                                         \
        const float* pr = xs + ((6 * s + g) << 4) + (wv << 2);                 \
        float4 p0 = *(const float4*)(pr);                                      \
        float4 p1 = *(const float4*)(pr + 16);                                 \
        float4 p2 = *(const float4*)(pr + 32);                                 \
        const float4* wr = (const float4*)(&wsm[0][0] + (WOFF))                \
                           + g * 192 + sl * 48 + o4;                           \
        float4 w0 = wr[0];                                                     \
        float4 w1 = wr[16];                                                    \
        float4 w2 = wr[32];                                                    \
        FMA16(p0, w0); FMA16(p1, w1); FMA16(p2, w2);                           \
    } }

__global__ __launch_bounds__(256, 2)
void lc2d_v9(const float* __restrict__ x,
             const float* __restrict__ weight,
             const float* __restrict__ bias,
             float* __restrict__ out) {
    __shared__ __align__(16) float xs[576 * 16];     // [row=(c*3+dh)*6+wl][b]
    __shared__ __align__(16) float wsm[3][12 * 256]; // [buf][3072 floats = 12 KB]

    const int tid  = threadIdx.x;
    const int lane = tid & 63;
    const int wv   = tid >> 6;        // wave id -> b-quad base 4*wv
    const int g    = lane >> 4;       // location offset 0..3
    const int o4   = lane & 15;       // o-quad (o = 4*o4 .. 4*o4+3)

    // XCD-contiguous bijective remap: 1024 blocks = 8 XCDs * 128.
    // XCD x owns locations [x*512, x*512+512): 64B out lines (4 blocks) merge in
    // ONE L2; x-slab (10h x 32c x 16b x 256B = 1.31 MB) is L2-resident per XCD.
    const int bid  = blockIdx.x;
    const int swz  = ((bid & 7) << 7) | (bid >> 3);
    const int l0   = swz * G_L;
    const int oh   = l0 >> 6;
    const int ow0  = l0 & 63;

    // ---- per-wave DMA piece setup: pieces p = wv, wv+4, wv+8 of each 12 KB chunk
    const float* gsrc[3];
    int ldsoff[3];
#pragma unroll
    for (int t = 0; t < 3; ++t) {
        int p   = wv + (t << 2);      // 0..11, wave-uniform
        int gg  = p / 3;
        int sub = p - 3 * gg;
        gsrc[t] = weight + (size_t)(l0 + gg) * (288 * 64) + sub * 256 + (lane << 2);
        ldsoff[t] = p * 256;          // float offset of piece base in wsm[buf]
    }

    // ---- prologue: DMA chunks 0 AND 1 (2-deep) while filling the x tile ----
#pragma unroll
    for (int t = 0; t < 3; ++t)
        __builtin_amdgcn_global_load_lds((f32g*)(gsrc[t]),
                                         (f32l*)(&wsm[0][ldsoff[t]]), 16, 0, 0);
#pragma unroll
    for (int t = 0; t < 3; ++t)
        __builtin_amdgcn_global_load_lds((f32g*)(gsrc[t] + CHUNK_STRIDE_F),
                                         (f32l*)(&wsm[1][ldsoff[t]]), 16, 0, 0);

    // ---- in-block coalesced x fill (replaces the xt pre-kernel entirely).
    // 192 wave-tasks: task = (j<<2)+wv, j = 0..47. Task -> (t = c*3+dh, bhalf);
    // lane -> (bq = lane>>3, w8 = lane&7); b = bhalf*8+bq.
    // Each inst: 8 b-segments of 8 consecutive w (32 B) -> ~8 L2-local lines,
    // vs 64 single-use lines/inst in the old b-strided gather.
    // Clamped address + select-0 (no exec churn -> loads pipeline freely).
    // Entire fill (~900 cyc/wave) hides under the 2-chunk DMA flight.
    {
        const int bq = lane >> 3;                 // 0..7
        const int w8 = lane & 7;                  // 0..7 (need 0..5)
        const int ww = ow0 - 1 + w8;              // -1..66
        const bool wok = (unsigned)ww < 64u;
        const int wwc = wok ? ww : 0;             // clamped
#pragma unroll 8
        for (int j = 0; j < 48; ++j) {
            int task  = (j << 2) + wv;            // 0..191, wave-uniform
            int bhalf = task & 1;
            int t     = task >> 1;                // c*3 + dh, 0..95
            int c     = t / 3;                    // magic-mul
            int dh    = t - 3 * c;
            int h     = oh - 1 + dh;
            bool hok  = (unsigned)h < 64u;
            int hc    = hok ? h : 0;              // clamped
            float v = x[((size_t)((bhalf << 3) + bq) << 17)
                        + (((c << 6) + hc) << 6) + wwc];
            v = (hok && wok) ? v : 0.0f;
            if (w8 < 6)
                xs[(t * 6 + w8) * 16 + (bhalf << 3) + bq] = v;
        }
    }
    __syncthreads();   // full drain: DMA(0),DMA(1) + x fill resident for everyone

    const float4 bias4 = ((const float4*)bias)[(l0 + g) * 16 + o4];
    float acc[4][4];
#pragma unroll
    for (int bq = 0; bq < 4; ++bq) {
        acc[bq][0] = bias4.x; acc[bq][1] = bias4.y;
        acc[bq][2] = bias4.z; acc[bq][3] = bias4.w;
    }

    // ---- main pipeline: 3 buffers, 2 chunks in flight, never vmcnt(0).
    int wo0 = 0;              // holds chunk k
    int wo1 = 12 * 256;       // holds chunk k+1
    int wo2 = 2 * 12 * 256;   // DMA target for chunk k+2
    for (int k = 0; k < NCHUNK - 2; ++k) {
#pragma unroll
        for (int t = 0; t < 3; ++t)
            __builtin_amdgcn_global_load_lds(
                (f32g*)(gsrc[t] + (size_t)(k + 2) * CHUNK_STRIDE_F),
                (f32l*)(&wsm[0][0] + wo2 + ldsoff[t]), 16, 0, 0);
        COMPUTE4(k, wo0);
        asm volatile("s_waitcnt vmcnt(3) lgkmcnt(0)" ::: "memory");
        __builtin_amdgcn_s_barrier();
        asm volatile("" ::: "memory");
        int tmp = wo0; wo0 = wo1; wo1 = wo2; wo2 = tmp;
    }
    // tail: chunk 22 resident; drain DMA(23) fully, then finish
    COMPUTE4(NCHUNK - 2, wo0);
    asm volatile("s_waitcnt vmcnt(0) lgkmcnt(0)" ::: "memory");
    __builtin_amdgcn_s_barrier();
    asm volatile("" ::: "memory");
    COMPUTE4(NCHUNK - 1, wo1);

    // ---- stores: out[((b*64 + o) << 12) + l0 + g], b = 4*wv+bq, o = 4*o4+j
#pragma unroll
    for (int bq = 0; bq < 4; ++bq) {
        const int b = (wv << 2) + bq;
#pragma unroll
        for (int j = 0; j < 4; ++j) {
            out[((size_t)((b << 6) + (o4 << 2) + j) << 12) + l0 + g] = acc[bq][j];
        }
    }
}

extern "C" void kernel_launch(void* const* d_in, const int* in_sizes, int n_in,
                              void* d_out, int out_size, void* d_ws, size_t ws_size,
                              hipStream_t stream) {
    const float* x      = (const float*)d_in[0];
    const float* weight = (const float*)d_in[1];
    const float* bias   = (const float*)d_in[2];
    float* out          = (float*)d_out;

    dim3 grid(L_TOT / G_L);   // 1024 blocks = 2 resident/CU
    dim3 block(256);
    hipLaunchKernelGGL(lc2d_v9, grid, block, 0, stream, x, weight, bias, out);
}